// Round 16
// baseline (121.023 us; speedup 1.0000x reference)
//
#include <hip/hip_runtime.h>
#include <math.h>

// Problem constants (shapes fixed by the reference):
// N=10000, E=640000, D=128, H1=256, H2=256, OUT=64
#define D_DIM   128
#define H1_DIM  256
#define H2_DIM  256
#define OUT_DIM 64
#define LN_EPS  1e-5f
#define NSHARD  4          // CSR counter shards per dst (contention 64 -> 16)
// aggP: bf16 A-fragment groups of 16 nodes; 4 kt x 64 lanes x 8 shorts
#define AGGP_STRIDE 2048   // shorts per group (MUST match allocation!)

typedef __attribute__((ext_vector_type(8))) short bf16x8;   // 8 bf16 (4 VGPRs)
typedef __attribute__((ext_vector_type(4))) float f32x4;    // MFMA acc

__device__ __forceinline__ unsigned short bf16rne(float v) {
    unsigned int b = __float_as_uint(v);
    return (unsigned short)((b + 0x7FFFu + ((b >> 16) & 1u)) >> 16);
}

union BFPack { unsigned int u[4]; bf16x8 v; };

// ---------------------------------------------------------------------------
// K1 (MFMA): y_bf16 = bf16(x @ pool_w) + packed per-node stats computed FROM
// the bf16-rounded y. 512 threads / 16 rows / 625 blocks.
// Fused extras: sharded dst-histogram slice; blocks 0-31 pack MLP weights.
// ---------------------------------------------------------------------------
__global__ __launch_bounds__(512) void k_pool(
        const float* __restrict__ x, const float* __restrict__ pw,
        const float* __restrict__ pb,
        unsigned short* __restrict__ y, float4* __restrict__ stat4,
        const int* __restrict__ ei, int* __restrict__ cnt, int E, int epb,
        const float* __restrict__ w1, const float* __restrict__ w2,
        const float* __restrict__ muw, const float* __restrict__ lvw,
        short* __restrict__ wp1, short* __restrict__ wp2,
        short* __restrict__ wpH) {
    __shared__ __align__(16) short aPack[4 * 64 * 8];      // 4 KB bf16 A-frags
    __shared__ unsigned short yLds[16][128];               // 4 KB bf16 y tile
    __shared__ float sPart[16][8][3];
    const int tid  = threadIdx.x;
    const int w    = tid >> 6;
    const int lane = tid & 63;
    const int gq   = lane >> 4;
    const int c16  = lane & 15;
    const int row0 = blockIdx.x * 16;

    // ---- B-frags for wave's col-tile ct=w (scattered f32 -> bf16)
    bf16x8 bfrag[4];
    {
        const int col = w * 16 + c16;
        const int kbase = gq * 8;
#pragma unroll
        for (int kt = 0; kt < 4; ++kt) {
            int k0 = kt * 32 + kbase;
            BFPack t;
#pragma unroll
            for (int jj = 0; jj < 4; ++jj) {
                float a = pw[(k0 + 2 * jj) * D_DIM + col];
                float b = pw[(k0 + 2 * jj + 1) * D_DIM + col];
                t.u[jj] = (unsigned int)bf16rne(a) | ((unsigned int)bf16rne(b) << 16);
            }
            bfrag[kt] = t.v;
        }
    }
    // ---- sharded histogram slice (fire-and-forget, overlaps everything)
    {
        int ebeg = blockIdx.x * epb;
        int eend = ebeg + epb; if (eend > E) eend = E;
        for (int e = ebeg + tid; e < eend; e += 512)
            atomicAdd(&cnt[ei[E + e] * NSHARD + (e & (NSHARD - 1))], 1);
    }
    // ---- stage x (16x128 f32) -> bf16 A-frags
    {
        int r  = tid >> 5;
        int k0 = (tid & 31) * 4;
        float4 v = *(const float4*)&x[(size_t)(row0 + r) * D_DIM + k0];
        int kt = k0 >> 5, sub = (k0 >> 3) & 3, j = k0 & 7;
        int lp = r | (sub << 4);
        unsigned int u0 = (unsigned int)bf16rne(v.x) | ((unsigned int)bf16rne(v.y) << 16);
        unsigned int u1 = (unsigned int)bf16rne(v.z) | ((unsigned int)bf16rne(v.w) << 16);
        *(uint2*)&aPack[kt * 512 + lp * 8 + j] = make_uint2(u0, u1);
    }
    __syncthreads();

    // ---- 4 MFMAs: D col = w*16 + c16, rows gq*4 + r
    f32x4 A = {0.f, 0.f, 0.f, 0.f};
#pragma unroll
    for (int kt = 0; kt < 4; ++kt) {
        bf16x8 av = *(bf16x8*)&aPack[(kt * 64 + lane) * 8];
        A = __builtin_amdgcn_mfma_f32_16x16x32_bf16(av, bfrag[kt], A, 0, 0, 0);
    }

    // ---- bf16-round, stash to yLds, per-row stats from the ROUNDED values
    {
        float pbf = pb[w * 16 + c16];
#pragma unroll
        for (int r = 0; r < 4; ++r) {
            unsigned short h = bf16rne(A[r]);
            yLds[gq * 4 + r][w * 16 + c16] = h;
            float hf = __uint_as_float((unsigned int)h << 16);
            float s1 = hf, s2 = hf * hf, s3 = hf * pbf;
#pragma unroll
            for (int m = 1; m < 16; m <<= 1) {
                s1 += __shfl_xor(s1, m, 64);
                s2 += __shfl_xor(s2, m, 64);
                s3 += __shfl_xor(s3, m, 64);
            }
            if (c16 == 0) {
                sPart[gq * 4 + r][w][0] = s1;
                sPart[gq * 4 + r][w][1] = s2;
                sPart[gq * 4 + r][w][2] = s3;
            }
        }
    }
    __syncthreads();
    {
        int idx = tid * 4;
        int r = idx >> 7, c = idx & 127;
        *(uint2*)&y[(size_t)(row0 + r) * D_DIM + c] = *(const uint2*)&yLds[r][c];
    }
    if (tid < 16) {
        float t1 = 0.f, t2 = 0.f, t3 = 0.f;
#pragma unroll
        for (int ww = 0; ww < 8; ++ww) {
            t1 += sPart[tid][ww][0]; t2 += sPart[tid][ww][1]; t3 += sPart[tid][ww][2];
        }
        stat4[row0 + tid] = make_float4(t1 * (1.f / 128.f), t2 * (1.f / 128.f),
                                        t3 * (1.f / 128.f), 0.f);
    }
    // ---- weight packing tail: blocks 0-31 x 512 threads = 16384 frag-lanes
    if (blockIdx.x < 32) {
        int i = blockIdx.x * 512 + tid;      // 0..16383
        const float* W; int Ndim, kt, ln, col; short* dst;
        if (i < 4096) {                      // w1: K=128 (KT=4), N=256 (16 ct)
            int q = i >> 6; ln = i & 63; kt = q & 3; int ct = q >> 2;
            W = w1; Ndim = H1_DIM; col = ct * 16 + (ln & 15); dst = wp1 + i * 8;
        } else if (i < 12288) {              // w2: K=256 (KT=8), N=256
            int i2 = i - 4096; int q = i2 >> 6; ln = i2 & 63; kt = q & 7; int ct = q >> 3;
            W = w2; Ndim = H2_DIM; col = ct * 16 + (ln & 15); dst = wp2 + i2 * 8;
        } else {                             // heads: K=256 (KT=8), ct 0-3 mu, 4-7 lv
            int i3 = i - 12288; int q = i3 >> 6; ln = i3 & 63; kt = q & 7; int ct = q >> 3;
            Ndim = OUT_DIM; dst = wpH + i3 * 8;
            if (ct < 4) { W = muw; col = ct * 16 + (ln & 15); }
            else        { W = lvw; col = (ct - 4) * 16 + (ln & 15); }
        }
        int k0 = kt * 32 + (ln >> 4) * 8;
        unsigned int u[4];
#pragma unroll
        for (int jj = 0; jj < 4; ++jj) {
            float a = W[(k0 + 2 * jj) * Ndim + col];
            float b = W[(k0 + 2 * jj + 1) * Ndim + col];
            u[jj] = (unsigned int)bf16rne(a) | ((unsigned int)bf16rne(b) << 16);
        }
        *(uint4*)dst = make_uint4(u[0], u[1], u[2], u[3]);
    }
}

// ---------------------------------------------------------------------------
// K2b-A: per-block scan (40 x 1024, coalesced, LDS Hillis-Steele).
// ---------------------------------------------------------------------------
__global__ __launch_bounds__(1024) void k_scanA(
        const int* __restrict__ cnt, int* __restrict__ offs,
        int* __restrict__ bsum, int N4) {
    __shared__ int part[1024];
    const int t = threadIdx.x;
    const int idx = blockIdx.x * 1024 + t;
    int v = (idx < N4) ? cnt[idx] : 0;
    part[t] = v;
    __syncthreads();
    for (int off = 1; off < 1024; off <<= 1) {
        int n = (t >= off) ? part[t - off] : 0;
        __syncthreads();
        part[t] += n;
        __syncthreads();
    }
    if (idx < N4) offs[idx] = part[t] - v;
    if (t == 1023) bsum[blockIdx.x] = part[t];
}

// ---------------------------------------------------------------------------
// K2b-B: single-wave scan of block totals; consts fold.
// ---------------------------------------------------------------------------
__global__ __launch_bounds__(64) void k_scanB(
        const int* __restrict__ bsum, int* __restrict__ bbase,
        int* __restrict__ offs, float* __restrict__ consts,
        const float* __restrict__ ewmc, const float* __restrict__ pb,
        int nblk, int N4) {
    const int l = threadIdx.x;
    {
        float v0 = pb[l], v1 = pb[l + 64];
        float s1 = v0 + v1, s2 = v0 * v0 + v1 * v1;
#pragma unroll
        for (int off = 1; off < 64; off <<= 1) {
            s1 += __shfl_xor(s1, off, 64);
            s2 += __shfl_xor(s2, off, 64);
        }
        if (l == 0) {
            float xw = ewmc[0];
            consts[0] = (xw > 30.f) ? xw : log1pf(expf(xw));
            consts[1] = s1 * (1.f / 128.f);
            consts[2] = s2 * (1.f / 128.f);
        }
    }
    int val = (l < nblk) ? bsum[l] : 0;
    int orig = val;
#pragma unroll
    for (int off = 1; off < 64; off <<= 1) {
        int n = __shfl_up(val, off, 64);
        if (l >= off) val += n;
    }
    if (l < nblk) bbase[l] = val - orig;
    if (l == nblk - 1) offs[N4] = val;
}

// ---------------------------------------------------------------------------
// K2b-C: add block bases; materialize head.
// ---------------------------------------------------------------------------
__global__ __launch_bounds__(1024) void k_scanC(
        int* __restrict__ offs, int* __restrict__ head,
        const int* __restrict__ bbase, int N4) {
    int idx = blockIdx.x * 1024 + threadIdx.x;
    if (idx < N4) {
        int o = offs[idx] + bbase[blockIdx.x];
        offs[idx] = o;
        head[idx] = o;
    }
}

// ---------------------------------------------------------------------------
// K2c: scatter edges into sharded CSR as float2 {src_bits, s} (8 B/edge —
// per-edge LN stats m,inv are recomputed in gather from stat4).
// 8 edges/thread, phase-separated (loads || atomics || writes).
// ---------------------------------------------------------------------------
__global__ __launch_bounds__(256) void k_scatter(
        const int* __restrict__ ei, const float* __restrict__ es,
        const float* __restrict__ consts,
        int* __restrict__ head, float2* __restrict__ pairs, int E) {
    const float coef = consts[0];
    const int tid = threadIdx.x;
    const int e0 = blockIdx.x * 2048 + tid;   // edges e0 + u*256, u=0..7
    int srcv[8]; int idxv[8]; float sv[8]; int pos[8]; bool ok[8];
#pragma unroll
    for (int u = 0; u < 8; ++u) {
        int e = e0 + u * 256;
        ok[u] = (e < E);
        if (ok[u]) {
            srcv[u] = ei[e];
            idxv[u] = ei[E + e] * NSHARD + (e & (NSHARD - 1));
            sv[u] = es[e];
        }
    }
#pragma unroll
    for (int u = 0; u < 8; ++u) if (ok[u])
        pos[u] = atomicAdd(&head[idxv[u]], 1);
#pragma unroll
    for (int u = 0; u < 8; ++u) if (ok[u]) {
        float s = fmaf(coef, sv[u], 1.0f);
        pairs[pos[u]] = make_float2(__int_as_float(srcv[u]), s);
    }
}

// ---------------------------------------------------------------------------
// K2d: gather-max per dst node, bf16 y, 8B pairs. One wave per node; 4 edges
// per wave (16 lanes x 8 dims each, 16B y loads), 12 edges in flight.
// m,inv recomputed per edge from stat4[src] (16-lane broadcast, L2-hot) —
// bit-identical to the scatter-side computation it replaces.
// ---------------------------------------------------------------------------
#define GPROC(S, M, INV, YB)                                                  \
    {                                                                         \
        float s = (S), m = (M), inv = (INV);                                  \
        float y0 = __uint_as_float((YB).x << 16);                             \
        float y1 = __uint_as_float((YB).x & 0xFFFF0000u);                     \
        float y2 = __uint_as_float((YB).y << 16);                             \
        float y3 = __uint_as_float((YB).y & 0xFFFF0000u);                     \
        float y4 = __uint_as_float((YB).z << 16);                             \
        float y5 = __uint_as_float((YB).z & 0xFFFF0000u);                     \
        float y6 = __uint_as_float((YB).w << 16);                             \
        float y7 = __uint_as_float((YB).w & 0xFFFF0000u);                     \
        mxA.x = fmaxf(mxA.x, fmaf(fmaf(s, y0, pbA.x) - m, inv * gA.x, bA.x)); \
        mxA.y = fmaxf(mxA.y, fmaf(fmaf(s, y1, pbA.y) - m, inv * gA.y, bA.y)); \
        mxA.z = fmaxf(mxA.z, fmaf(fmaf(s, y2, pbA.z) - m, inv * gA.z, bA.z)); \
        mxA.w = fmaxf(mxA.w, fmaf(fmaf(s, y3, pbA.w) - m, inv * gA.w, bA.w)); \
        mxB.x = fmaxf(mxB.x, fmaf(fmaf(s, y4, pbB.x) - m, inv * gB.x, bB.x)); \
        mxB.y = fmaxf(mxB.y, fmaf(fmaf(s, y5, pbB.y) - m, inv * gB.y, bB.y)); \
        mxB.z = fmaxf(mxB.z, fmaf(fmaf(s, y6, pbB.z) - m, inv * gB.z, bB.z)); \
        mxB.w = fmaxf(mxB.w, fmaf(fmaf(s, y7, pbB.w) - m, inv * gB.w, bB.w)); \
    }

// compute m, inv for edge (s, st) — identical expressions to old scatter
#define GSTAT(S, ST, M, INV)                                                  \
    float M   = fmaf((S), (ST).x, mpb);                                       \
    float INV;                                                                \
    {                                                                         \
        float et2 = fmaf((S) * (S), (ST).y, fmaf(2.f * (S), (ST).z, mpb2));   \
        INV = rsqrtf(et2 - M * M + LN_EPS);                                   \
    }

__global__ __launch_bounds__(256) void k_gather(
        const float2* __restrict__ pairs, const int* __restrict__ offs,
        const float* __restrict__ consts, const float4* __restrict__ stat4,
        const unsigned short* __restrict__ y, const float* __restrict__ pb,
        const float* __restrict__ g, const float* __restrict__ b,
        unsigned short* __restrict__ aggP, int N) {
    const int node = blockIdx.x * 4 + (threadIdx.x >> 6);
    if (node >= N) return;
    const float mpb = consts[1], mpb2 = consts[2];
    const int lane = threadIdx.x & 63;
    const int sub  = lane >> 4;          // edge slot 0..3
    const int q    = lane & 15;          // dim octet: dims q*8 .. q*8+7
    const int d0   = q * 8;
    const float4 pbA = *(const float4*)&pb[d0], pbB = *(const float4*)&pb[d0 + 4];
    const float4 gA  = *(const float4*)&g[d0],  gB  = *(const float4*)&g[d0 + 4];
    const float4 bA  = *(const float4*)&b[d0],  bB  = *(const float4*)&b[d0 + 4];
    float4 mxA = make_float4(-INFINITY, -INFINITY, -INFINITY, -INFINITY);
    float4 mxB = mxA;
    int j = offs[node * NSHARD];
    const int end = offs[node * NSHARD + NSHARD];
    for (; j + 12 <= end; j += 12) {
        float2 p[3]; float4 st[3]; uint4 yb[3];
#pragma unroll
        for (int u = 0; u < 3; ++u) p[u] = pairs[j + 4 * u + sub];
#pragma unroll
        for (int u = 0; u < 3; ++u) {
            int src = __float_as_int(p[u].x);
            st[u] = stat4[src];
            yb[u] = *(const uint4*)&y[(size_t)src * D_DIM + d0];
        }
#pragma unroll
        for (int u = 0; u < 3; ++u) {
            GSTAT(p[u].y, st[u], m_, inv_);
            GPROC(p[u].y, m_, inv_, yb[u]);
        }
    }
    for (; j + 4 <= end; j += 4) {
        float2 p = pairs[j + sub];
        int src = __float_as_int(p.x);
        float4 st = stat4[src];
        uint4 yb = *(const uint4*)&y[(size_t)src * D_DIM + d0];
        GSTAT(p.y, st, m_, inv_);
        GPROC(p.y, m_, inv_, yb);
    }
    if (j < end) {                       // rem 1..3: dup edges harmless
        int rem = end - j;
        float2 p = pairs[j + (sub < rem ? sub : 0)];
        int src = __float_as_int(p.x);
        float4 st = stat4[src];
        uint4 yb = *(const uint4*)&y[(size_t)src * D_DIM + d0];
        GSTAT(p.y, st, m_, inv_);
        GPROC(p.y, m_, inv_, yb);
    }
    // merge the four quarter-wave partials
    mxA.x = fmaxf(mxA.x, __shfl_xor(mxA.x, 16, 64));
    mxA.y = fmaxf(mxA.y, __shfl_xor(mxA.y, 16, 64));
    mxA.z = fmaxf(mxA.z, __shfl_xor(mxA.z, 16, 64));
    mxA.w = fmaxf(mxA.w, __shfl_xor(mxA.w, 16, 64));
    mxB.x = fmaxf(mxB.x, __shfl_xor(mxB.x, 16, 64));
    mxB.y = fmaxf(mxB.y, __shfl_xor(mxB.y, 16, 64));
    mxB.z = fmaxf(mxB.z, __shfl_xor(mxB.z, 16, 64));
    mxB.w = fmaxf(mxB.w, __shfl_xor(mxB.w, 16, 64));
    mxA.x = fmaxf(mxA.x, __shfl_xor(mxA.x, 32, 64));
    mxA.y = fmaxf(mxA.y, __shfl_xor(mxA.y, 32, 64));
    mxA.z = fmaxf(mxA.z, __shfl_xor(mxA.z, 32, 64));
    mxA.w = fmaxf(mxA.w, __shfl_xor(mxA.w, 32, 64));
    mxB.x = fmaxf(mxB.x, __shfl_xor(mxB.x, 32, 64));
    mxB.y = fmaxf(mxB.y, __shfl_xor(mxB.y, 32, 64));
    mxB.z = fmaxf(mxB.z, __shfl_xor(mxB.z, 32, 64));
    mxB.w = fmaxf(mxB.w, __shfl_xor(mxB.w, 32, 64));
    if (sub == 0) {
        unsigned int u0 = (unsigned int)bf16rne(fmaxf(mxA.x, 0.f))
                        | ((unsigned int)bf16rne(fmaxf(mxA.y, 0.f)) << 16);
        unsigned int u1 = (unsigned int)bf16rne(fmaxf(mxA.z, 0.f))
                        | ((unsigned int)bf16rne(fmaxf(mxA.w, 0.f)) << 16);
        unsigned int u2 = (unsigned int)bf16rne(fmaxf(mxB.x, 0.f))
                        | ((unsigned int)bf16rne(fmaxf(mxB.y, 0.f)) << 16);
        unsigned int u3 = (unsigned int)bf16rne(fmaxf(mxB.z, 0.f))
                        | ((unsigned int)bf16rne(fmaxf(mxB.w, 0.f)) << 16);
        int kt = q >> 2, sfr = q & 3, lp = (node & 15) | (sfr << 4);
        *(uint4*)&aggP[(size_t)(node >> 4) * AGGP_STRIDE + kt * 512 + lp * 8] =
            make_uint4(u0, u1, u2, u3);
    }
}

// ---------------------------------------------------------------------------
// K3: MFMA MLP. 512 threads (8 waves), 16 rows/block, 625 blocks.
// Layer-1 A-fragments come PRE-PACKED from aggP (global, bf16, L1-broadcast).
// ---------------------------------------------------------------------------
__global__ __launch_bounds__(512) void k_mlp(
        const unsigned short* __restrict__ aggP,
        const short* __restrict__ wp1, const short* __restrict__ wp2,
        const short* __restrict__ wpH,
        const float* __restrict__ b1, const float* __restrict__ g1,
        const float* __restrict__ bb1,
        const float* __restrict__ b2, const float* __restrict__ g2,
        const float* __restrict__ bb2,
        const float* __restrict__ mub, const float* __restrict__ lvb,
        float* __restrict__ out, int N) {
    __shared__ __align__(16) short aPack[8 * 64 * 8];   // 8 KB: K up to 256
    __shared__ float sPart[16][8][2];
    __shared__ float sM[16], sI[16];
    const int tid  = threadIdx.x;
    const int w    = tid >> 6;
    const int lane = tid & 63;
    const int gq   = lane >> 4;
    const int c16  = lane & 15;
    const int row0 = blockIdx.x * 16;
    const unsigned short* aG = aggP + (size_t)blockIdx.x * AGGP_STRIDE;

    const int ct0 = 2 * w, ct1 = 2 * w + 1;
    f32x4 A0 = {0.f, 0.f, 0.f, 0.f}, A1 = {0.f, 0.f, 0.f, 0.f};

    // ---- layer 1: K=128, A-frags straight from global
#pragma unroll
    for (int kt = 0; kt < 4; ++kt) {
        bf16x8 av = *(const bf16x8*)&aG[(kt * 64 + lane) * 8];
        bf16x8 bv0 = *(const bf16x8*)&wp1[((ct0 * 4 + kt) * 64 + lane) * 8];
        bf16x8 bv1 = *(const bf16x8*)&wp1[((ct1 * 4 + kt) * 64 + lane) * 8];
        A0 = __builtin_amdgcn_mfma_f32_16x16x32_bf16(av, bv0, A0, 0, 0, 0);
        A1 = __builtin_amdgcn_mfma_f32_16x16x32_bf16(av, bv1, A1, 0, 0, 0);
    }
    {
        int col0 = ct0 * 16 + c16, col1 = ct1 * 16 + c16;
        float bias0 = b1[col0], bias1 = b1[col1];
        float v0[4], v1[4];
#pragma unroll
        for (int r = 0; r < 4; ++r) {
            v0[r] = A0[r] + bias0; v1[r] = A1[r] + bias1;
            float s1 = v0[r] + v1[r];
            float s2 = v0[r] * v0[r] + v1[r] * v1[r];
#pragma unroll
            for (int m = 1; m < 16; m <<= 1) {
                s1 += __shfl_xor(s1, m, 64);
                s2 += __shfl_xor(s2, m, 64);
            }
            if (c16 == 0) { sPart[gq * 4 + r][w][0] = s1; sPart[gq * 4 + r][w][1] = s2; }
        }
        __syncthreads();
        if (tid < 16) {
            float t1 = 0.f, t2 = 0.f;
#pragma unroll
            for (int ww = 0; ww < 8; ++ww) { t1 += sPart[tid][ww][0]; t2 += sPart[tid][ww][1]; }
            float m = t1 * (1.f / 256.f);
            sM[tid] = m;
            sI[tid] = rsqrtf(t2 * (1.f / 256.f) - m * m + LN_EPS);
        }
        __syncthreads();
        float gc0 = g1[col0], bc0 = bb1[col0];
        float gc1 = g1[col1], bc1 = bb1[col1];
#pragma unroll
        for (int r = 0; r < 4; ++r) {
            int row = gq * 4 + r;
            float m = sM[row], inv = sI[row];
            float h0 = fmaxf(fmaf((v0[r] - m) * inv, gc0, bc0), 0.f);
            float h1 = fmaxf(fmaf((v1[r] - m) * inv, gc1, bc1), 0.f);
            aPack[(col0 >> 5) * 512 + (row | (((col0 >> 3) & 3) << 4)) * 8 + (col0 & 7)] = (short)bf16rne(h0);
            aPack[(col1 >> 5) * 512 + (row | (((col1 >> 3) & 3) << 4)) * 8 + (col1 & 7)] = (short)bf16rne(h1);
        }
    }
    __syncthreads();

    // ---- layer 2: K=256
    A0 = (f32x4){0.f, 0.f, 0.f, 0.f}; A1 = (f32x4){0.f, 0.f, 0.f, 0.f};
#pragma unroll
    for (int kt = 0; kt < 8; ++kt) {
        bf16x8 av = *(bf16x8*)&aPack[(kt * 64 + lane) * 8];
        bf16x8 bv0 = *(const bf16x8*)&wp2[((ct0 * 8 + kt) * 64 + lane) * 8];
        bf16x8 bv1 = *(const bf16x8*)&wp2[((ct1 * 8 + kt) * 64 + lane) * 8];
        A0 = __builtin_amdgcn_mfma_f32_16x16x32_bf16(av, bv0, A0, 0, 0, 0);
        A1 = __builtin_amdgcn_mfma_f32_16x16x32_bf16(av, bv1, A1, 0, 0, 0);
    }
    {
        int col0 = ct0 * 16 + c16, col1 = ct1 * 16 + c16;
        float bias0 = b2[col0], bias1 = b2[col1];
        float v0[4], v1[4];
#pragma unroll
        for (int r = 0; r < 4; ++r) {
            v0[r] = A0[r] + bias0; v1[r] = A1[r] + bias1;
            float s1 = v0[r] + v1[r];
            float s2 = v0[r] * v0[r] + v1[r] * v1[r];
#pragma unroll
            for (int m = 1; m < 16; m <<= 1) {
                s1 += __shfl_xor(s1, m, 64);
                s2 += __shfl_xor(s2, m, 64);
            }
            if (c16 == 0) { sPart[gq * 4 + r][w][0] = s1; sPart[gq * 4 + r][w][1] = s2; }
        }
        __syncthreads();
        if (tid < 16) {
            float t1 = 0.f, t2 = 0.f;
#pragma unroll
            for (int ww = 0; ww < 8; ++ww) { t1 += sPart[tid][ww][0]; t2 += sPart[tid][ww][1]; }
            float m = t1 * (1.f / 256.f);
            sM[tid] = m;
            sI[tid] = rsqrtf(t2 * (1.f / 256.f) - m * m + LN_EPS);
        }
        __syncthreads();
        float gc0 = g2[col0], bc0 = bb2[col0];
        float gc1 = g2[col1], bc1 = bb2[col1];
#pragma unroll
        for (int r = 0; r < 4; ++r) {
            int row = gq * 4 + r;
            float m = sM[row], inv = sI[row];
            float h0 = fmaxf(fmaf((v0[r] - m) * inv, gc0, bc0), 0.f);
            float h1 = fmaxf(fmaf((v1[r] - m) * inv, gc1, bc1), 0.f);
            aPack[(col0 >> 5) * 512 + (row | (((col0 >> 3) & 3) << 4)) * 8 + (col0 & 7)] = (short)bf16rne(h0);
            aPack[(col1 >> 5) * 512 + (row | (((col1 >> 3) & 3) << 4)) * 8 + (col1 & 7)] = (short)bf16rne(h1);
        }
    }
    __syncthreads();

    // ---- heads
    {
        f32x4 H = {0.f, 0.f, 0.f, 0.f};
#pragma unroll
        for (int kt = 0; kt < 8; ++kt) {
            bf16x8 av = *(bf16x8*)&aPack[(kt * 64 + lane) * 8];
            bf16x8 bv = *(const bf16x8*)&wpH[((w * 8 + kt) * 64 + lane) * 8];
            H = __builtin_amdgcn_mfma_f32_16x16x32_bf16(av, bv, H, 0, 0, 0);
        }
        int colh = (w & 3) * 16 + c16;
        if (w < 4) {
            float bias = mub[colh];
#pragma unroll
            for (int r = 0; r < 4; ++r)
                out[(size_t)(row0 + gq * 4 + r) * OUT_DIM + colh] = H[r] + bias;
        } else {
            float bias = lvb[colh];
#pragma unroll
            for (int r = 0; r < 4; ++r)
                out[(size_t)N * OUT_DIM + (size_t)(row0 + gq * 4 + r) * OUT_DIM + colh] =
                    expf(0.5f * (H[r] + bias));
        }
    }
}

// ---------------------------------------------------------------------------
extern "C" void kernel_launch(void* const* d_in, const int* in_sizes, int n_in,
                              void* d_out, int out_size, void* d_ws, size_t ws_size,
                              hipStream_t stream) {
    const float* x      = (const float*)d_in[0];
    const int*   ei     = (const int*)  d_in[1];
    const float* es     = (const float*)d_in[2];
    const float* ewmc   = (const float*)d_in[3];
    const float* pool_w = (const float*)d_in[4];
    const float* pool_b = (const float*)d_in[5];
    const float* lnp_g  = (const float*)d_in[6];
    const float* lnp_b  = (const float*)d_in[7];
    const float* w1     = (const float*)d_in[8];
    const float* b1     = (const float*)d_in[9];
    const float* ln1_g  = (const float*)d_in[10];
    const float* ln1_b  = (const float*)d_in[11];
    const float* w2     = (const float*)d_in[12];
    const float* b2     = (const float*)d_in[13];
    const float* ln2_g  = (const float*)d_in[14];
    const float* ln2_b  = (const float*)d_in[15];
    const float* mu_w   = (const float*)d_in[16];
    const float* mu_b   = (const float*)d_in[17];
    const float* lv_w   = (const float*)d_in[18];
    const float* lv_b   = (const float*)d_in[19];

    const int N  = in_sizes[0] / D_DIM;   // 10000
    const int E  = in_sizes[2];           // 640000
    const int N4 = N * NSHARD;            // 40000 sharded counters
    const int nblkScan = (N4 + 1023) / 1024;   // 40

    // Workspace layout (4-byte words):
    // consts[16] | stat4[N] | y_bf16[N*64 w] | aggP[N*64 w] | cnt[N4] |
    // offs[N4+1] | head[N4] | bsum[64] | bbase[64] | (align) | wp1 | wp2 |
    // wpH | pairs[E] (float2)
    float*  ws     = (float*)d_ws;
    float*  consts = ws;
    float4* stat4  = (float4*)(ws + 16);
    unsigned short* y    = (unsigned short*)(ws + 16 + 4 * (size_t)N);
    unsigned short* aggP = y + (size_t)N * D_DIM;
    size_t  w      = 16 + 4 * (size_t)N + (size_t)N * D_DIM;  // y + aggP
    int*    cnt    = (int*)(ws + w); w += N4;
    int*    offs   = (int*)(ws + w); w += N4 + 1;
    int*    head   = (int*)(ws + w); w += N4;
    int*    bsum   = (int*)(ws + w); w += 64;
    int*    bbase  = (int*)(ws + w); w += 64;
    w = (w + 3) & ~(size_t)3;
    short*  wp1    = (short*)(ws + w); w += 16384;   // 32768 shorts
    short*  wp2    = (short*)(ws + w); w += 32768;   // 65536 shorts
    short*  wpH    = (short*)(ws + w); w += 16384;   // 32768 shorts
    float2* pairs  = (float2*)(ws + w);

    const int nbPool = N / 16;                     // 625 blocks
    const int epb    = (E + nbPool - 1) / nbPool;  // 1024 edges per block

    hipMemsetAsync(cnt, 0, (size_t)N4 * sizeof(int), stream);
    k_pool<<<nbPool, 512, 0, stream>>>(x, pool_w, pool_b, y, stat4, ei, cnt, E,
                                       epb, w1, w2, mu_w, lv_w, wp1, wp2, wpH);
    k_scanA<<<nblkScan, 1024, 0, stream>>>(cnt, offs, bsum, N4);
    k_scanB<<<1, 64, 0, stream>>>(bsum, bbase, offs, consts, ewmc, pool_b,
                                  nblkScan, N4);
    k_scanC<<<nblkScan, 1024, 0, stream>>>(offs, head, bbase, N4);
    k_scatter<<<(E + 2047) / 2048, 256, 0, stream>>>(ei, es, consts,
                                                     head, pairs, E);
    k_gather<<<(N + 3) / 4, 256, 0, stream>>>(pairs, offs, consts, stat4, y,
                                              pool_b, lnp_g, lnp_b, aggP, N);
    k_mlp<<<N / 16, 512, 0, stream>>>(aggP, wp1, wp2, wpH,
                                      b1, ln1_g, ln1_b,
                                      b2, ln2_g, ln2_b,
                                      mu_b, lv_b, (float*)d_out, N);
}

// Round 17
// 116.314 us; speedup vs baseline: 1.0405x; 1.0405x over previous
//
#include <hip/hip_runtime.h>
#include <math.h>

// Problem constants (shapes fixed by the reference):
// N=10000, E=640000, D=128, H1=256, H2=256, OUT=64
#define D_DIM   128
#define H1_DIM  256
#define H2_DIM  256
#define OUT_DIM 64
#define LN_EPS  1e-5f
#define NSHARD  4          // CSR counter shards per dst (contention 64 -> 16)
// aggP: bf16 A-fragment groups of 16 nodes; 4 kt x 64 lanes x 8 shorts
#define AGGP_STRIDE 2048   // shorts per group (MUST match allocation!)

typedef __attribute__((ext_vector_type(8))) short bf16x8;   // 8 bf16 (4 VGPRs)
typedef __attribute__((ext_vector_type(4))) float f32x4;    // MFMA acc

__device__ __forceinline__ unsigned short bf16rne(float v) {
    unsigned int b = __float_as_uint(v);
    return (unsigned short)((b + 0x7FFFu + ((b >> 16) & 1u)) >> 16);
}

union BFPack { unsigned int u[4]; bf16x8 v; };

// ---------------------------------------------------------------------------
// K1 (MFMA): y_bf16 = bf16(x @ pool_w) + packed per-node stats computed FROM
// the bf16-rounded y. 512 threads / 16 rows / 625 blocks.
// Fused extras: sharded dst-histogram slice; blocks 0-31 pack MLP weights.
// ---------------------------------------------------------------------------
__global__ __launch_bounds__(512) void k_pool(
        const float* __restrict__ x, const float* __restrict__ pw,
        const float* __restrict__ pb,
        unsigned short* __restrict__ y, float4* __restrict__ stat4,
        const int* __restrict__ ei, int* __restrict__ cnt, int E, int epb,
        const float* __restrict__ w1, const float* __restrict__ w2,
        const float* __restrict__ muw, const float* __restrict__ lvw,
        short* __restrict__ wp1, short* __restrict__ wp2,
        short* __restrict__ wpH) {
    __shared__ __align__(16) short aPack[4 * 64 * 8];      // 4 KB bf16 A-frags
    __shared__ unsigned short yLds[16][128];               // 4 KB bf16 y tile
    __shared__ float sPart[16][8][3];
    const int tid  = threadIdx.x;
    const int w    = tid >> 6;
    const int lane = tid & 63;
    const int gq   = lane >> 4;
    const int c16  = lane & 15;
    const int row0 = blockIdx.x * 16;

    // ---- B-frags for wave's col-tile ct=w (scattered f32 -> bf16)
    bf16x8 bfrag[4];
    {
        const int col = w * 16 + c16;
        const int kbase = gq * 8;
#pragma unroll
        for (int kt = 0; kt < 4; ++kt) {
            int k0 = kt * 32 + kbase;
            BFPack t;
#pragma unroll
            for (int jj = 0; jj < 4; ++jj) {
                float a = pw[(k0 + 2 * jj) * D_DIM + col];
                float b = pw[(k0 + 2 * jj + 1) * D_DIM + col];
                t.u[jj] = (unsigned int)bf16rne(a) | ((unsigned int)bf16rne(b) << 16);
            }
            bfrag[kt] = t.v;
        }
    }
    // ---- sharded histogram slice (fire-and-forget, overlaps everything)
    {
        int ebeg = blockIdx.x * epb;
        int eend = ebeg + epb; if (eend > E) eend = E;
        for (int e = ebeg + tid; e < eend; e += 512)
            atomicAdd(&cnt[ei[E + e] * NSHARD + (e & (NSHARD - 1))], 1);
    }
    // ---- stage x (16x128 f32) -> bf16 A-frags
    {
        int r  = tid >> 5;
        int k0 = (tid & 31) * 4;
        float4 v = *(const float4*)&x[(size_t)(row0 + r) * D_DIM + k0];
        int kt = k0 >> 5, sub = (k0 >> 3) & 3, j = k0 & 7;
        int lp = r | (sub << 4);
        unsigned int u0 = (unsigned int)bf16rne(v.x) | ((unsigned int)bf16rne(v.y) << 16);
        unsigned int u1 = (unsigned int)bf16rne(v.z) | ((unsigned int)bf16rne(v.w) << 16);
        *(uint2*)&aPack[kt * 512 + lp * 8 + j] = make_uint2(u0, u1);
    }
    __syncthreads();

    // ---- 4 MFMAs: D col = w*16 + c16, rows gq*4 + r
    f32x4 A = {0.f, 0.f, 0.f, 0.f};
#pragma unroll
    for (int kt = 0; kt < 4; ++kt) {
        bf16x8 av = *(bf16x8*)&aPack[(kt * 64 + lane) * 8];
        A = __builtin_amdgcn_mfma_f32_16x16x32_bf16(av, bfrag[kt], A, 0, 0, 0);
    }

    // ---- bf16-round, stash to yLds, per-row stats from the ROUNDED values
    {
        float pbf = pb[w * 16 + c16];
#pragma unroll
        for (int r = 0; r < 4; ++r) {
            unsigned short h = bf16rne(A[r]);
            yLds[gq * 4 + r][w * 16 + c16] = h;
            float hf = __uint_as_float((unsigned int)h << 16);
            float s1 = hf, s2 = hf * hf, s3 = hf * pbf;
#pragma unroll
            for (int m = 1; m < 16; m <<= 1) {
                s1 += __shfl_xor(s1, m, 64);
                s2 += __shfl_xor(s2, m, 64);
                s3 += __shfl_xor(s3, m, 64);
            }
            if (c16 == 0) {
                sPart[gq * 4 + r][w][0] = s1;
                sPart[gq * 4 + r][w][1] = s2;
                sPart[gq * 4 + r][w][2] = s3;
            }
        }
    }
    __syncthreads();
    {
        int idx = tid * 4;
        int r = idx >> 7, c = idx & 127;
        *(uint2*)&y[(size_t)(row0 + r) * D_DIM + c] = *(const uint2*)&yLds[r][c];
    }
    if (tid < 16) {
        float t1 = 0.f, t2 = 0.f, t3 = 0.f;
#pragma unroll
        for (int ww = 0; ww < 8; ++ww) {
            t1 += sPart[tid][ww][0]; t2 += sPart[tid][ww][1]; t3 += sPart[tid][ww][2];
        }
        stat4[row0 + tid] = make_float4(t1 * (1.f / 128.f), t2 * (1.f / 128.f),
                                        t3 * (1.f / 128.f), 0.f);
    }
    // ---- weight packing tail: blocks 0-31 x 512 threads = 16384 frag-lanes
    if (blockIdx.x < 32) {
        int i = blockIdx.x * 512 + tid;      // 0..16383
        const float* W; int Ndim, kt, ln, col; short* dst;
        if (i < 4096) {                      // w1: K=128 (KT=4), N=256 (16 ct)
            int q = i >> 6; ln = i & 63; kt = q & 3; int ct = q >> 2;
            W = w1; Ndim = H1_DIM; col = ct * 16 + (ln & 15); dst = wp1 + i * 8;
        } else if (i < 12288) {              // w2: K=256 (KT=8), N=256
            int i2 = i - 4096; int q = i2 >> 6; ln = i2 & 63; kt = q & 7; int ct = q >> 3;
            W = w2; Ndim = H2_DIM; col = ct * 16 + (ln & 15); dst = wp2 + i2 * 8;
        } else {                             // heads: K=256 (KT=8), ct 0-3 mu, 4-7 lv
            int i3 = i - 12288; int q = i3 >> 6; ln = i3 & 63; kt = q & 7; int ct = q >> 3;
            Ndim = OUT_DIM; dst = wpH + i3 * 8;
            if (ct < 4) { W = muw; col = ct * 16 + (ln & 15); }
            else        { W = lvw; col = (ct - 4) * 16 + (ln & 15); }
        }
        int k0 = kt * 32 + (ln >> 4) * 8;
        unsigned int u[4];
#pragma unroll
        for (int jj = 0; jj < 4; ++jj) {
            float a = W[(k0 + 2 * jj) * Ndim + col];
            float b = W[(k0 + 2 * jj + 1) * Ndim + col];
            u[jj] = (unsigned int)bf16rne(a) | ((unsigned int)bf16rne(b) << 16);
        }
        *(uint4*)dst = make_uint4(u[0], u[1], u[2], u[3]);
    }
}

// ---------------------------------------------------------------------------
// K2b-A: per-block scan (40 x 1024, coalesced, LDS Hillis-Steele).
// ---------------------------------------------------------------------------
__global__ __launch_bounds__(1024) void k_scanA(
        const int* __restrict__ cnt, int* __restrict__ offs,
        int* __restrict__ bsum, int N4) {
    __shared__ int part[1024];
    const int t = threadIdx.x;
    const int idx = blockIdx.x * 1024 + t;
    int v = (idx < N4) ? cnt[idx] : 0;
    part[t] = v;
    __syncthreads();
    for (int off = 1; off < 1024; off <<= 1) {
        int n = (t >= off) ? part[t - off] : 0;
        __syncthreads();
        part[t] += n;
        __syncthreads();
    }
    if (idx < N4) offs[idx] = part[t] - v;
    if (t == 1023) bsum[blockIdx.x] = part[t];
}

// ---------------------------------------------------------------------------
// K2b-B: single-wave scan of block totals; consts fold.
// ---------------------------------------------------------------------------
__global__ __launch_bounds__(64) void k_scanB(
        const int* __restrict__ bsum, int* __restrict__ bbase,
        int* __restrict__ offs, float* __restrict__ consts,
        const float* __restrict__ ewmc, const float* __restrict__ pb,
        int nblk, int N4) {
    const int l = threadIdx.x;
    {
        float v0 = pb[l], v1 = pb[l + 64];
        float s1 = v0 + v1, s2 = v0 * v0 + v1 * v1;
#pragma unroll
        for (int off = 1; off < 64; off <<= 1) {
            s1 += __shfl_xor(s1, off, 64);
            s2 += __shfl_xor(s2, off, 64);
        }
        if (l == 0) {
            float xw = ewmc[0];
            consts[0] = (xw > 30.f) ? xw : log1pf(expf(xw));
            consts[1] = s1 * (1.f / 128.f);
            consts[2] = s2 * (1.f / 128.f);
        }
    }
    int val = (l < nblk) ? bsum[l] : 0;
    int orig = val;
#pragma unroll
    for (int off = 1; off < 64; off <<= 1) {
        int n = __shfl_up(val, off, 64);
        if (l >= off) val += n;
    }
    if (l < nblk) bbase[l] = val - orig;
    if (l == nblk - 1) offs[N4] = val;
}

// ---------------------------------------------------------------------------
// K2b-C: add block bases; materialize head.
// ---------------------------------------------------------------------------
__global__ __launch_bounds__(1024) void k_scanC(
        int* __restrict__ offs, int* __restrict__ head,
        const int* __restrict__ bbase, int N4) {
    int idx = blockIdx.x * 1024 + threadIdx.x;
    if (idx < N4) {
        int o = offs[idx] + bbase[blockIdx.x];
        offs[idx] = o;
        head[idx] = o;
    }
}

// ---------------------------------------------------------------------------
// K2c: scatter edges into sharded CSR as float4 {src_bits, s, m, inv}.
// 8 edges/thread, phase-separated (loads || stat4 || atomics || writes).
// ---------------------------------------------------------------------------
__global__ __launch_bounds__(256) void k_scatter(
        const int* __restrict__ ei, const float* __restrict__ es,
        const float* __restrict__ consts, const float4* __restrict__ stat4,
        int* __restrict__ head, float4* __restrict__ pairs, int E) {
    const float coef = consts[0], mpb = consts[1], mpb2 = consts[2];
    const int tid = threadIdx.x;
    const int e0 = blockIdx.x * 2048 + tid;   // edges e0 + u*256, u=0..7
    int srcv[8], dstv[8]; float sv[8]; float4 st[8]; int pos[8]; bool ok[8];
#pragma unroll
    for (int u = 0; u < 8; ++u) {
        int e = e0 + u * 256;
        ok[u] = (e < E);
        if (ok[u]) { srcv[u] = ei[e]; dstv[u] = ei[E + e]; sv[u] = es[e]; }
    }
#pragma unroll
    for (int u = 0; u < 8; ++u) if (ok[u]) st[u] = stat4[srcv[u]];
#pragma unroll
    for (int u = 0; u < 8; ++u) if (ok[u]) {
        int e = e0 + u * 256;
        pos[u] = atomicAdd(&head[dstv[u] * NSHARD + (e & (NSHARD - 1))], 1);
    }
#pragma unroll
    for (int u = 0; u < 8; ++u) if (ok[u]) {
        float s = fmaf(coef, sv[u], 1.0f);
        float m   = fmaf(s, st[u].x, mpb);
        float et2 = fmaf(s * s, st[u].y, fmaf(2.f * s, st[u].z, mpb2));
        float inv = rsqrtf(et2 - m * m + LN_EPS);
        pairs[pos[u]] = make_float4(__int_as_float(srcv[u]), s, m, inv);
    }
}

// ---------------------------------------------------------------------------
// K2d: gather-max per dst node, bf16 y. One wave per node; 4 edges per wave
// (16 lanes x 8 dims each, 16B loads), 12 edges in flight. Output written
// as relu'd bf16 directly in MFMA A-fragment order to aggP (global):
//   group = node>>4, kt = q>>2, lp = (node&15)|((q&3)<<4)
//   addr(shorts) = group*AGGP_STRIDE + kt*512 + lp*8
// ---------------------------------------------------------------------------
#define GPROC(P, YB)                                                          \
    {                                                                         \
        float s = (P).y, m = (P).z, inv = (P).w;                              \
        float y0 = __uint_as_float((YB).x << 16);                             \
        float y1 = __uint_as_float((YB).x & 0xFFFF0000u);                     \
        float y2 = __uint_as_float((YB).y << 16);                             \
        float y3 = __uint_as_float((YB).y & 0xFFFF0000u);                     \
        float y4 = __uint_as_float((YB).z << 16);                             \
        float y5 = __uint_as_float((YB).z & 0xFFFF0000u);                     \
        float y6 = __uint_as_float((YB).w << 16);                             \
        float y7 = __uint_as_float((YB).w & 0xFFFF0000u);                     \
        mxA.x = fmaxf(mxA.x, fmaf(fmaf(s, y0, pbA.x) - m, inv * gA.x, bA.x)); \
        mxA.y = fmaxf(mxA.y, fmaf(fmaf(s, y1, pbA.y) - m, inv * gA.y, bA.y)); \
        mxA.z = fmaxf(mxA.z, fmaf(fmaf(s, y2, pbA.z) - m, inv * gA.z, bA.z)); \
        mxA.w = fmaxf(mxA.w, fmaf(fmaf(s, y3, pbA.w) - m, inv * gA.w, bA.w)); \
        mxB.x = fmaxf(mxB.x, fmaf(fmaf(s, y4, pbB.x) - m, inv * gB.x, bB.x)); \
        mxB.y = fmaxf(mxB.y, fmaf(fmaf(s, y5, pbB.y) - m, inv * gB.y, bB.y)); \
        mxB.z = fmaxf(mxB.z, fmaf(fmaf(s, y6, pbB.z) - m, inv * gB.z, bB.z)); \
        mxB.w = fmaxf(mxB.w, fmaf(fmaf(s, y7, pbB.w) - m, inv * gB.w, bB.w)); \
    }

__global__ __launch_bounds__(256) void k_gather(
        const float4* __restrict__ pairs, const int* __restrict__ offs,
        const unsigned short* __restrict__ y, const float* __restrict__ pb,
        const float* __restrict__ g, const float* __restrict__ b,
        unsigned short* __restrict__ aggP, int N) {
    const int node = blockIdx.x * 4 + (threadIdx.x >> 6);
    if (node >= N) return;
    const int lane = threadIdx.x & 63;
    const int sub  = lane >> 4;          // edge slot 0..3
    const int q    = lane & 15;          // dim octet: dims q*8 .. q*8+7
    const int d0   = q * 8;
    const float4 pbA = *(const float4*)&pb[d0], pbB = *(const float4*)&pb[d0 + 4];
    const float4 gA  = *(const float4*)&g[d0],  gB  = *(const float4*)&g[d0 + 4];
    const float4 bA  = *(const float4*)&b[d0],  bB  = *(const float4*)&b[d0 + 4];
    float4 mxA = make_float4(-INFINITY, -INFINITY, -INFINITY, -INFINITY);
    float4 mxB = mxA;
    int j = offs[node * NSHARD];
    const int end = offs[node * NSHARD + NSHARD];
    for (; j + 12 <= end; j += 12) {
        float4 p[3]; uint4 yb[3];
#pragma unroll
        for (int u = 0; u < 3; ++u) p[u] = pairs[j + 4 * u + sub];
#pragma unroll
        for (int u = 0; u < 3; ++u)
            yb[u] = *(const uint4*)&y[(size_t)__float_as_int(p[u].x) * D_DIM + d0];
#pragma unroll
        for (int u = 0; u < 3; ++u) GPROC(p[u], yb[u]);
    }
    for (; j + 4 <= end; j += 4) {
        float4 p = pairs[j + sub];
        uint4 yb = *(const uint4*)&y[(size_t)__float_as_int(p.x) * D_DIM + d0];
        GPROC(p, yb);
    }
    if (j < end) {                       // rem 1..3: dup edges harmless
        int rem = end - j;
        float4 p = pairs[j + (sub < rem ? sub : 0)];
        uint4 yb = *(const uint4*)&y[(size_t)__float_as_int(p.x) * D_DIM + d0];
        GPROC(p, yb);
    }
    // merge the four quarter-wave partials
    mxA.x = fmaxf(mxA.x, __shfl_xor(mxA.x, 16, 64));
    mxA.y = fmaxf(mxA.y, __shfl_xor(mxA.y, 16, 64));
    mxA.z = fmaxf(mxA.z, __shfl_xor(mxA.z, 16, 64));
    mxA.w = fmaxf(mxA.w, __shfl_xor(mxA.w, 16, 64));
    mxB.x = fmaxf(mxB.x, __shfl_xor(mxB.x, 16, 64));
    mxB.y = fmaxf(mxB.y, __shfl_xor(mxB.y, 16, 64));
    mxB.z = fmaxf(mxB.z, __shfl_xor(mxB.z, 16, 64));
    mxB.w = fmaxf(mxB.w, __shfl_xor(mxB.w, 16, 64));
    mxA.x = fmaxf(mxA.x, __shfl_xor(mxA.x, 32, 64));
    mxA.y = fmaxf(mxA.y, __shfl_xor(mxA.y, 32, 64));
    mxA.z = fmaxf(mxA.z, __shfl_xor(mxA.z, 32, 64));
    mxA.w = fmaxf(mxA.w, __shfl_xor(mxA.w, 32, 64));
    mxB.x = fmaxf(mxB.x, __shfl_xor(mxB.x, 32, 64));
    mxB.y = fmaxf(mxB.y, __shfl_xor(mxB.y, 32, 64));
    mxB.z = fmaxf(mxB.z, __shfl_xor(mxB.z, 32, 64));
    mxB.w = fmaxf(mxB.w, __shfl_xor(mxB.w, 32, 64));
    if (sub == 0) {
        unsigned int u0 = (unsigned int)bf16rne(fmaxf(mxA.x, 0.f))
                        | ((unsigned int)bf16rne(fmaxf(mxA.y, 0.f)) << 16);
        unsigned int u1 = (unsigned int)bf16rne(fmaxf(mxA.z, 0.f))
                        | ((unsigned int)bf16rne(fmaxf(mxA.w, 0.f)) << 16);
        unsigned int u2 = (unsigned int)bf16rne(fmaxf(mxB.x, 0.f))
                        | ((unsigned int)bf16rne(fmaxf(mxB.y, 0.f)) << 16);
        unsigned int u3 = (unsigned int)bf16rne(fmaxf(mxB.z, 0.f))
                        | ((unsigned int)bf16rne(fmaxf(mxB.w, 0.f)) << 16);
        int kt = q >> 2, sfr = q & 3, lp = (node & 15) | (sfr << 4);
        *(uint4*)&aggP[(size_t)(node >> 4) * AGGP_STRIDE + kt * 512 + lp * 8] =
            make_uint4(u0, u1, u2, u3);
    }
}

// ---------------------------------------------------------------------------
// K3: MFMA MLP. 512 threads (8 waves), 16 rows/block, 625 blocks.
// Layer-1 A-fragments come PRE-PACKED from aggP (global, bf16, L1-broadcast).
// ---------------------------------------------------------------------------
__global__ __launch_bounds__(512) void k_mlp(
        const unsigned short* __restrict__ aggP,
        const short* __restrict__ wp1, const short* __restrict__ wp2,
        const short* __restrict__ wpH,
        const float* __restrict__ b1, const float* __restrict__ g1,
        const float* __restrict__ bb1,
        const float* __restrict__ b2, const float* __restrict__ g2,
        const float* __restrict__ bb2,
        const float* __restrict__ mub, const float* __restrict__ lvb,
        float* __restrict__ out, int N) {
    __shared__ __align__(16) short aPack[8 * 64 * 8];   // 8 KB: K up to 256
    __shared__ float sPart[16][8][2];
    __shared__ float sM[16], sI[16];
    const int tid  = threadIdx.x;
    const int w    = tid >> 6;
    const int lane = tid & 63;
    const int gq   = lane >> 4;
    const int c16  = lane & 15;
    const int row0 = blockIdx.x * 16;
    const unsigned short* aG = aggP + (size_t)blockIdx.x * AGGP_STRIDE;

    const int ct0 = 2 * w, ct1 = 2 * w + 1;
    f32x4 A0 = {0.f, 0.f, 0.f, 0.f}, A1 = {0.f, 0.f, 0.f, 0.f};

    // ---- layer 1: K=128, A-frags straight from global
#pragma unroll
    for (int kt = 0; kt < 4; ++kt) {
        bf16x8 av = *(const bf16x8*)&aG[(kt * 64 + lane) * 8];
        bf16x8 bv0 = *(const bf16x8*)&wp1[((ct0 * 4 + kt) * 64 + lane) * 8];
        bf16x8 bv1 = *(const bf16x8*)&wp1[((ct1 * 4 + kt) * 64 + lane) * 8];
        A0 = __builtin_amdgcn_mfma_f32_16x16x32_bf16(av, bv0, A0, 0, 0, 0);
        A1 = __builtin_amdgcn_mfma_f32_16x16x32_bf16(av, bv1, A1, 0, 0, 0);
    }
    {
        int col0 = ct0 * 16 + c16, col1 = ct1 * 16 + c16;
        float bias0 = b1[col0], bias1 = b1[col1];
        float v0[4], v1[4];
#pragma unroll
        for (int r = 0; r < 4; ++r) {
            v0[r] = A0[r] + bias0; v1[r] = A1[r] + bias1;
            float s1 = v0[r] + v1[r];
            float s2 = v0[r] * v0[r] + v1[r] * v1[r];
#pragma unroll
            for (int m = 1; m < 16; m <<= 1) {
                s1 += __shfl_xor(s1, m, 64);
                s2 += __shfl_xor(s2, m, 64);
            }
            if (c16 == 0) { sPart[gq * 4 + r][w][0] = s1; sPart[gq * 4 + r][w][1] = s2; }
        }
        __syncthreads();
        if (tid < 16) {
            float t1 = 0.f, t2 = 0.f;
#pragma unroll
            for (int ww = 0; ww < 8; ++ww) { t1 += sPart[tid][ww][0]; t2 += sPart[tid][ww][1]; }
            float m = t1 * (1.f / 256.f);
            sM[tid] = m;
            sI[tid] = rsqrtf(t2 * (1.f / 256.f) - m * m + LN_EPS);
        }
        __syncthreads();
        float gc0 = g1[col0], bc0 = bb1[col0];
        float gc1 = g1[col1], bc1 = bb1[col1];
#pragma unroll
        for (int r = 0; r < 4; ++r) {
            int row = gq * 4 + r;
            float m = sM[row], inv = sI[row];
            float h0 = fmaxf(fmaf((v0[r] - m) * inv, gc0, bc0), 0.f);
            float h1 = fmaxf(fmaf((v1[r] - m) * inv, gc1, bc1), 0.f);
            aPack[(col0 >> 5) * 512 + (row | (((col0 >> 3) & 3) << 4)) * 8 + (col0 & 7)] = (short)bf16rne(h0);
            aPack[(col1 >> 5) * 512 + (row | (((col1 >> 3) & 3) << 4)) * 8 + (col1 & 7)] = (short)bf16rne(h1);
        }
    }
    __syncthreads();

    // ---- layer 2: K=256
    A0 = (f32x4){0.f, 0.f, 0.f, 0.f}; A1 = (f32x4){0.f, 0.f, 0.f, 0.f};
#pragma unroll
    for (int kt = 0; kt < 8; ++kt) {
        bf16x8 av = *(bf16x8*)&aPack[(kt * 64 + lane) * 8];
        bf16x8 bv0 = *(const bf16x8*)&wp2[((ct0 * 8 + kt) * 64 + lane) * 8];
        bf16x8 bv1 = *(const bf16x8*)&wp2[((ct1 * 8 + kt) * 64 + lane) * 8];
        A0 = __builtin_amdgcn_mfma_f32_16x16x32_bf16(av, bv0, A0, 0, 0, 0);
        A1 = __builtin_amdgcn_mfma_f32_16x16x32_bf16(av, bv1, A1, 0, 0, 0);
    }
    {
        int col0 = ct0 * 16 + c16, col1 = ct1 * 16 + c16;
        float bias0 = b2[col0], bias1 = b2[col1];
        float v0[4], v1[4];
#pragma unroll
        for (int r = 0; r < 4; ++r) {
            v0[r] = A0[r] + bias0; v1[r] = A1[r] + bias1;
            float s1 = v0[r] + v1[r];
            float s2 = v0[r] * v0[r] + v1[r] * v1[r];
#pragma unroll
            for (int m = 1; m < 16; m <<= 1) {
                s1 += __shfl_xor(s1, m, 64);
                s2 += __shfl_xor(s2, m, 64);
            }
            if (c16 == 0) { sPart[gq * 4 + r][w][0] = s1; sPart[gq * 4 + r][w][1] = s2; }
        }
        __syncthreads();
        if (tid < 16) {
            float t1 = 0.f, t2 = 0.f;
#pragma unroll
            for (int ww = 0; ww < 8; ++ww) { t1 += sPart[tid][ww][0]; t2 += sPart[tid][ww][1]; }
            float m = t1 * (1.f / 256.f);
            sM[tid] = m;
            sI[tid] = rsqrtf(t2 * (1.f / 256.f) - m * m + LN_EPS);
        }
        __syncthreads();
        float gc0 = g2[col0], bc0 = bb2[col0];
        float gc1 = g2[col1], bc1 = bb2[col1];
#pragma unroll
        for (int r = 0; r < 4; ++r) {
            int row = gq * 4 + r;
            float m = sM[row], inv = sI[row];
            float h0 = fmaxf(fmaf((v0[r] - m) * inv, gc0, bc0), 0.f);
            float h1 = fmaxf(fmaf((v1[r] - m) * inv, gc1, bc1), 0.f);
            aPack[(col0 >> 5) * 512 + (row | (((col0 >> 3) & 3) << 4)) * 8 + (col0 & 7)] = (short)bf16rne(h0);
            aPack[(col1 >> 5) * 512 + (row | (((col1 >> 3) & 3) << 4)) * 8 + (col1 & 7)] = (short)bf16rne(h1);
        }
    }
    __syncthreads();

    // ---- heads
    {
        f32x4 H = {0.f, 0.f, 0.f, 0.f};
#pragma unroll
        for (int kt = 0; kt < 8; ++kt) {
            bf16x8 av = *(bf16x8*)&aPack[(kt * 64 + lane) * 8];
            bf16x8 bv = *(const bf16x8*)&wpH[((w * 8 + kt) * 64 + lane) * 8];
            H = __builtin_amdgcn_mfma_f32_16x16x32_bf16(av, bv, H, 0, 0, 0);
        }
        int colh = (w & 3) * 16 + c16;
        if (w < 4) {
            float bias = mub[colh];
#pragma unroll
            for (int r = 0; r < 4; ++r)
                out[(size_t)(row0 + gq * 4 + r) * OUT_DIM + colh] = H[r] + bias;
        } else {
            float bias = lvb[colh];
#pragma unroll
            for (int r = 0; r < 4; ++r)
                out[(size_t)N * OUT_DIM + (size_t)(row0 + gq * 4 + r) * OUT_DIM + colh] =
                    expf(0.5f * (H[r] + bias));
        }
    }
}

// ---------------------------------------------------------------------------
extern "C" void kernel_launch(void* const* d_in, const int* in_sizes, int n_in,
                              void* d_out, int out_size, void* d_ws, size_t ws_size,
                              hipStream_t stream) {
    const float* x      = (const float*)d_in[0];
    const int*   ei     = (const int*)  d_in[1];
    const float* es     = (const float*)d_in[2];
    const float* ewmc   = (const float*)d_in[3];
    const float* pool_w = (const float*)d_in[4];
    const float* pool_b = (const float*)d_in[5];
    const float* lnp_g  = (const float*)d_in[6];
    const float* lnp_b  = (const float*)d_in[7];
    const float* w1     = (const float*)d_in[8];
    const float* b1     = (const float*)d_in[9];
    const float* ln1_g  = (const float*)d_in[10];
    const float* ln1_b  = (const float*)d_in[11];
    const float* w2     = (const float*)d_in[12];
    const float* b2     = (const float*)d_in[13];
    const float* ln2_g  = (const float*)d_in[14];
    const float* ln2_b  = (const float*)d_in[15];
    const float* mu_w   = (const float*)d_in[16];
    const float* mu_b   = (const float*)d_in[17];
    const float* lv_w   = (const float*)d_in[18];
    const float* lv_b   = (const float*)d_in[19];

    const int N  = in_sizes[0] / D_DIM;   // 10000
    const int E  = in_sizes[2];           // 640000
    const int N4 = N * NSHARD;            // 40000 sharded counters
    const int nblkScan = (N4 + 1023) / 1024;   // 40

    // Workspace layout (4-byte words):
    // consts[16] | stat4[N] | y_bf16[N*64 w] | aggP[N*64 w] | cnt[N4] |
    // offs[N4+1] | head[N4] | bsum[64] | bbase[64] | (align) | wp1 | wp2 |
    // wpH | pairs[E] (float4)
    float*  ws     = (float*)d_ws;
    float*  consts = ws;
    float4* stat4  = (float4*)(ws + 16);
    unsigned short* y    = (unsigned short*)(ws + 16 + 4 * (size_t)N);
    unsigned short* aggP = y + (size_t)N * D_DIM;
    size_t  w      = 16 + 4 * (size_t)N + (size_t)N * D_DIM;  // y + aggP
    int*    cnt    = (int*)(ws + w); w += N4;
    int*    offs   = (int*)(ws + w); w += N4 + 1;
    int*    head   = (int*)(ws + w); w += N4;
    int*    bsum   = (int*)(ws + w); w += 64;
    int*    bbase  = (int*)(ws + w); w += 64;
    w = (w + 3) & ~(size_t)3;
    short*  wp1    = (short*)(ws + w); w += 16384;   // 32768 shorts
    short*  wp2    = (short*)(ws + w); w += 32768;   // 65536 shorts
    short*  wpH    = (short*)(ws + w); w += 16384;   // 32768 shorts
    float4* pairs  = (float4*)(ws + w);

    const int nbPool = N / 16;                     // 625 blocks
    const int epb    = (E + nbPool - 1) / nbPool;  // 1024 edges per block

    hipMemsetAsync(cnt, 0, (size_t)N4 * sizeof(int), stream);
    k_pool<<<nbPool, 512, 0, stream>>>(x, pool_w, pool_b, y, stat4, ei, cnt, E,
                                       epb, w1, w2, mu_w, lv_w, wp1, wp2, wpH);
    k_scanA<<<nblkScan, 1024, 0, stream>>>(cnt, offs, bsum, N4);
    k_scanB<<<1, 64, 0, stream>>>(bsum, bbase, offs, consts, ewmc, pool_b,
                                  nblkScan, N4);
    k_scanC<<<nblkScan, 1024, 0, stream>>>(offs, head, bbase, N4);
    k_scatter<<<(E + 2047) / 2048, 256, 0, stream>>>(ei, es, consts, stat4,
                                                     head, pairs, E);
    k_gather<<<(N + 3) / 4, 256, 0, stream>>>(pairs, offs, y,
                                              pool_b, lnp_g, lnp_b, aggP, N);
    k_mlp<<<N / 16, 512, 0, stream>>>(aggP, wp1, wp2, wpH,
                                      b1, ln1_g, ln1_b,
                                      b2, ln2_g, ln2_b,
                                      mu_b, lv_b, (float*)d_out, N);
}